// Round 9
// baseline (671.522 us; speedup 1.0000x reference)
//
#include <hip/hip_runtime.h>
#include <hip/hip_bf16.h>

#define B_  4096
#define T_  255
#define V_  32000
#define E_  64
#define H_  64
#define D1_ 32

#define NCT           2000   // V/16 col-tiles
#define NCHUNK        10
#define CT_PER_CHUNK  200    // NCT / NCHUNK
#define CT_PER_WAVE   50     // CT_PER_CHUNK / 4 waves

#define LSTM_REPS     3      // calibration: run the recurrence 3x (state reset
                             // each rep; rep 2 owns the output). zx_dur =
                             // (total_R9 - total_R8) / 2; 3x dispatch > fills
                             // so lstm enters rocprof top-5 WITH counters.

typedef __attribute__((ext_vector_type(8))) short bf16x8;   // 8 bf16 = 4 VGPR
typedef __attribute__((ext_vector_type(4))) float f32x4;

__device__ __forceinline__ ushort f2bf(float f) {
    __hip_bfloat16 h = __float2bfloat16(f);   // RNE
    return *reinterpret_cast<ushort*>(&h);
}
__device__ __forceinline__ float fast_sigmoid(float x) {
    return __builtin_amdgcn_rcpf(1.f + __expf(-x));
}
__device__ __forceinline__ float fast_tanh(float x) {
    return 1.f - 2.f * __builtin_amdgcn_rcpf(1.f + __expf(2.f * x));
}

// Swizzled byte offset in a [16 rows][64 bf16] (128 B/row) h-tile.
__device__ __forceinline__ int hswz(int row, int colb) {
    return row * 128 + (colb ^ ((row & 7) << 4));
}

// ---------------------------------------------------------------------------
// Kernel 0 (merged): blocks [0,1000): emb fp32->bf16 ; [1000,1500): W2 repack.
// ---------------------------------------------------------------------------
__global__ __launch_bounds__(256)
void prep_kernel(const float* __restrict__ emb, ushort* __restrict__ emb_bf,
                 const float* __restrict__ W2,  ushort* __restrict__ w2p)
{
    if (blockIdx.x < 1000) {
        int i = blockIdx.x * 256 + threadIdx.x;      // over V*64/8 = 256000
        const float4 a = ((const float4*)emb)[i * 2];
        const float4 b = ((const float4*)emb)[i * 2 + 1];
        ushort t[8] = { f2bf(a.x), f2bf(a.y), f2bf(a.z), f2bf(a.w),
                        f2bf(b.x), f2bf(b.y), f2bf(b.z), f2bf(b.w) };
        *(ushort4*)(&emb_bf[i * 8])     = *(ushort4*)(&t[0]);
        *(ushort4*)(&emb_bf[i * 8 + 4]) = *(ushort4*)(&t[4]);
    } else {
        int t = (blockIdx.x - 1000) * 256 + threadIdx.x;   // over NCT*64
        if (t >= NCT * 64) return;
        int ct = t >> 6, l = t & 63;
        int kbase = (l >> 4) * 8, c = ct * 16 + (l & 15);
        ushort tmp[8];
        #pragma unroll
        for (int i = 0; i < 8; ++i)
            tmp[i] = f2bf(W2[(kbase + i) * V_ + c]);
        *(ushort4*)(&w2p[t * 8])     = *(ushort4*)(&tmp[0]);
        *(ushort4*)(&w2p[t * 8 + 4]) = *(ushort4*)(&tmp[4]);
    }
}

// ===========================================================================
// LSTM, bf16 MFMA, zx-precompute — byte-identical math to R8, wrapped in a
// LSTM_REPS calibration loop (full state/pipeline reset per rep).
// ===========================================================================
__global__ __launch_bounds__(256)
void lstm_mfma_kernel(const int* __restrict__ idx,
                      const ushort* __restrict__ emb_bf,
                      const float* __restrict__ Wx,
                      const float* __restrict__ Wh,
                      const float* __restrict__ b,
                      float* __restrict__ h_out)
{
    __shared__ __align__(16) char hbuf[2][2048];   // [buf][16 rows][64 bf16]
    __shared__ int idxs[16 * 257];                 // [row][t], stride 257

    const int tid  = threadIdx.x;
    const int lane = tid & 63;
    const int w    = tid >> 6;          // unit group
    const int r0   = blockIdx.x * 16;
    const int lrow = lane & 15;
    const int lhi  = lane >> 4;
    const int jcol = w * 16 + lrow;

    // persistent B fragments: 4 gates x 4 K-slices (s=0,1: Wx ; s=2,3: Wh)
    bf16x8 bw[16];
    float bias[4];
    #pragma unroll
    for (int g = 0; g < 4; ++g) {
        const int col = g * 64 + jcol;
        bias[g] = b[col];
        #pragma unroll
        for (int s = 0; s < 4; ++s) {
            bf16x8 f;
            #pragma unroll
            for (int i = 0; i < 8; ++i) {
                int k = s * 32 + lhi * 8 + i;
                float v = (k < 64) ? Wx[k * 256 + col] : Wh[(k - 64) * 256 + col];
                f[i] = (short)f2bf(v);
            }
            bw[g * 4 + s] = f;
        }
    }

    {
        const int row = tid >> 4, tc = tid & 15;
        #pragma unroll
        for (int k = 0; k < 16; ++k) {
            int t = k * 16 + tc;
            if (t < T_) idxs[row * 257 + t] = idx[(r0 + row) * T_ + t];
        }
    }
    __syncthreads();   // idxs visible

    float cst[4], hreg[4];

    for (int rep = 0; rep < LSTM_REPS; ++rep) {
        // reset h-buffer 0 and state (prior rep's reads of hbuf[0] completed
        // before its trailing barrier)
        ((float2*)hbuf[0])[tid] = make_float2(0.f, 0.f);
        #pragma unroll
        for (int r = 0; r < 4; ++r) { cst[r] = 0.f; hreg[r] = 0.f; }

        // ---- prologue: zx(0), zx(1); x(2), x(3) in flight ----
        f32x4 zxe[4], zxo[4];
        bf16x8 xe0, xe1, xo0, xo1;
        {
            int iv = idxs[lrow * 257 + 0];
            bf16x8 a0 = *(const bf16x8*)(emb_bf + iv * 64 + lhi * 8);
            bf16x8 a1 = *(const bf16x8*)(emb_bf + iv * 64 + 32 + lhi * 8);
            #pragma unroll
            for (int g = 0; g < 4; ++g) {
                zxe[g] = (f32x4){bias[g], bias[g], bias[g], bias[g]};
                zxe[g] = __builtin_amdgcn_mfma_f32_16x16x32_bf16(a0, bw[g * 4 + 0], zxe[g], 0, 0, 0);
                zxe[g] = __builtin_amdgcn_mfma_f32_16x16x32_bf16(a1, bw[g * 4 + 1], zxe[g], 0, 0, 0);
            }
            iv = idxs[lrow * 257 + 1];
            a0 = *(const bf16x8*)(emb_bf + iv * 64 + lhi * 8);
            a1 = *(const bf16x8*)(emb_bf + iv * 64 + 32 + lhi * 8);
            #pragma unroll
            for (int g = 0; g < 4; ++g) {
                zxo[g] = (f32x4){bias[g], bias[g], bias[g], bias[g]};
                zxo[g] = __builtin_amdgcn_mfma_f32_16x16x32_bf16(a0, bw[g * 4 + 0], zxo[g], 0, 0, 0);
                zxo[g] = __builtin_amdgcn_mfma_f32_16x16x32_bf16(a1, bw[g * 4 + 1], zxo[g], 0, 0, 0);
            }
            iv = idxs[lrow * 257 + 2];
            xe0 = *(const bf16x8*)(emb_bf + iv * 64 + lhi * 8);
            xe1 = *(const bf16x8*)(emb_bf + iv * 64 + 32 + lhi * 8);
            iv = idxs[lrow * 257 + 3];
            xo0 = *(const bf16x8*)(emb_bf + iv * 64 + lhi * 8);
            xo1 = *(const bf16x8*)(emb_bf + iv * 64 + 32 + lhi * 8);
        }
        __syncthreads();   // hbuf[0] zeroed & visible

        auto do_step = [&](int t, f32x4* zx, bf16x8& x0, bf16x8& x1) {
            const int p = t & 1;
            bf16x8 ah2 = *(const bf16x8*)(&hbuf[p][hswz(lrow, lhi * 16)]);
            bf16x8 ah3 = *(const bf16x8*)(&hbuf[p][hswz(lrow, 64 + lhi * 16)]);

            // z = zx + h @ Wh   (2-deep chain, 4 parallel gates)
            f32x4 z[4];
            #pragma unroll
            for (int g = 0; g < 4; ++g)
                z[g] = __builtin_amdgcn_mfma_f32_16x16x32_bf16(ah2, bw[g * 4 + 2], zx[g], 0, 0, 0);
            #pragma unroll
            for (int g = 0; g < 4; ++g)
                z[g] = __builtin_amdgcn_mfma_f32_16x16x32_bf16(ah3, bw[g * 4 + 3], z[g], 0, 0, 0);

            // recompute this slot's zx for t+2 (x loaded 2 steps ago)
            if (t + 2 < T_) {
                #pragma unroll
                for (int g = 0; g < 4; ++g) {
                    zx[g] = (f32x4){bias[g], bias[g], bias[g], bias[g]};
                    zx[g] = __builtin_amdgcn_mfma_f32_16x16x32_bf16(x0, bw[g * 4 + 0], zx[g], 0, 0, 0);
                    zx[g] = __builtin_amdgcn_mfma_f32_16x16x32_bf16(x1, bw[g * 4 + 1], zx[g], 0, 0, 0);
                }
            }
            // reload this x slot for t+4 (in flight across 2 barriers)
            if (t + 4 < T_) {
                int iv = idxs[lrow * 257 + (t + 4)];
                x0 = *(const bf16x8*)(emb_bf + iv * 64 + lhi * 8);
                x1 = *(const bf16x8*)(emb_bf + iv * 64 + 32 + lhi * 8);
            }

            // activation (wave-local)
            #pragma unroll
            for (int r = 0; r < 4; ++r) {
                float cn = fast_sigmoid(z[1][r]) * cst[r]
                         + fast_sigmoid(z[0][r]) * fast_tanh(z[2][r]);
                cst[r] = cn;
                float hn = fast_sigmoid(z[3][r]) * fast_tanh(cn);
                hreg[r] = hn;
                const int row = lhi * 4 + r;
                *(ushort*)(&hbuf[p ^ 1][hswz(row, 2 * jcol)]) = f2bf(hn);
            }

            // LDS-only fence + raw barrier (global loads stay in flight)
            asm volatile("s_waitcnt lgkmcnt(0)\n\ts_barrier" ::: "memory");
        };

        for (int t = 0; t + 1 < T_; t += 2) {
            do_step(t,     zxe, xe0, xe1);
            do_step(t + 1, zxo, xo0, xo1);
        }
        do_step(T_ - 1, zxe, xe0, xe1);   // T_=255 odd: tail = even-slot step
    }

    #pragma unroll
    for (int r = 0; r < 4; ++r)
        h_out[(r0 + lhi * 4 + r) * H_ + jcol] = hreg[r];
}

// ---------------------------------------------------------------------------
// Kernel 2: out32bf = bf16(relu(h @ W1 + b1))   [4096,64]@[64,32]
// ---------------------------------------------------------------------------
__global__ __launch_bounds__(256)
void head1_kernel(const float* __restrict__ h,
                  const float* __restrict__ W1,
                  const float* __restrict__ b1,
                  ushort* __restrict__ out32bf)
{
    int i = blockIdx.x * 256 + threadIdx.x;   // over 4096*32
    int r = i >> 5, d = i & 31;
    float a = b1[d];
    #pragma unroll
    for (int k = 0; k < 64; ++k)
        a = fmaf(h[r * H_ + k], W1[k * D1_ + d], a);
    out32bf[i] = f2bf(fmaxf(a, 0.f));
}

// ---------------------------------------------------------------------------
// Kernel 3: logits = out32 @ W2 + b2, softmax over V, via MFMA.
// ---------------------------------------------------------------------------
template <int PASS>
__global__ __launch_bounds__(256)
void head2_mfma_kernel(const ushort* __restrict__ out32bf,
                       const ushort* __restrict__ w2p,
                       const float* __restrict__ b2,
                       float* __restrict__ partial,   // [B][NCHUNK]
                       float* __restrict__ out)
{
    __shared__ float red[4][16];
    __shared__ float sinvs[16];

    const int tid  = threadIdx.x;
    const int lane = tid & 63;
    const int w    = tid >> 6;
    const int lrow = lane & 15;
    const int lhi  = lane >> 4;
    const int r0    = blockIdx.x * 16;
    const int chunk = blockIdx.y;

    if (PASS == 2) {
        if (tid < 16) {
            float s = 0.f;
            #pragma unroll
            for (int c = 0; c < NCHUNK; ++c) s += partial[(r0 + tid) * NCHUNK + c];
            sinvs[tid] = 1.f / s;
        }
        __syncthreads();
    }

    const bf16x8 A = *(const bf16x8*)(out32bf + (r0 + lrow) * D1_ + lhi * 8);

    float sacc[4] = {0.f, 0.f, 0.f, 0.f};
    float si[4];
    if (PASS == 2) {
        #pragma unroll
        for (int r = 0; r < 4; ++r) si[r] = sinvs[lhi * 4 + r];
    }

    const int ct0 = chunk * CT_PER_CHUNK + w * CT_PER_WAVE;
    for (int i = 0; i < CT_PER_WAVE; ++i) {
        const int ct = ct0 + i;
        const bf16x8 Bf = *(const bf16x8*)(w2p + ct * 512 + lane * 8);
        f32x4 z = __builtin_amdgcn_mfma_f32_16x16x32_bf16(A, Bf, (f32x4){0.f, 0.f, 0.f, 0.f}, 0, 0, 0);
        const float b2v = b2[ct * 16 + lrow];
        #pragma unroll
        for (int r = 0; r < 4; ++r) {
            float e = __expf(z[r] + b2v);
            if (PASS == 1) sacc[r] += e;
            else out[(size_t)(r0 + lhi * 4 + r) * V_ + ct * 16 + lrow] = e * si[r];
        }
    }

    if (PASS == 1) {
        #pragma unroll
        for (int r = 0; r < 4; ++r) {
            float v = sacc[r];
            #pragma unroll
            for (int off = 1; off < 16; off <<= 1) v += __shfl_xor(v, off, 16);
            if (lrow == 0) red[w][lhi * 4 + r] = v;
        }
        __syncthreads();
        if (tid < 16)
            partial[(r0 + tid) * NCHUNK + chunk] =
                red[0][tid] + red[1][tid] + red[2][tid] + red[3][tid];
    }
}

// ---------------------------------------------------------------------------
extern "C" void kernel_launch(void* const* d_in, const int* in_sizes, int n_in,
                              void* d_out, int out_size, void* d_ws, size_t ws_size,
                              hipStream_t stream)
{
    (void)in_sizes; (void)n_in; (void)out_size; (void)ws_size;

    const int*   idx = (const int*)  d_in[0];
    const float* emb = (const float*)d_in[1];
    const float* Wx  = (const float*)d_in[2];
    const float* Wh  = (const float*)d_in[3];
    const float* bl  = (const float*)d_in[4];
    const float* W1  = (const float*)d_in[5];
    const float* b1  = (const float*)d_in[6];
    const float* W2  = (const float*)d_in[7];
    const float* b2  = (const float*)d_in[8];
    float* out = (float*)d_out;

    float*  ws      = (float*)d_ws;
    float*  h       = ws;                                    // 262144 f32
    ushort* out32bf = (ushort*)(ws + 262144);                // 131072 us
    ushort* w2p     = (ushort*)(ws + 262144 + 65536);        // 1024000 us
    float*  part    = ws + 262144 + 65536 + 512000;          // 40960 f32
    ushort* emb_bf  = (ushort*)(ws + 262144 + 65536 + 512000 + 40960);  // 2048000 us

    prep_kernel<<<1500, 256, 0, stream>>>(emb, emb_bf, W2, w2p);
    lstm_mfma_kernel<<<256, 256, 0, stream>>>(idx, emb_bf, Wx, Wh, bl, h);
    head1_kernel<<<(B_ * D1_) / 256, 256, 0, stream>>>(h, W1, b1, out32bf);

    dim3 g3(B_ / 16, NCHUNK);
    head2_mfma_kernel<1><<<g3, 256, 0, stream>>>(out32bf, w2p, b2, part, out);
    head2_mfma_kernel<2><<<g3, 256, 0, stream>>>(out32bf, w2p, b2, part, out);
}

// Round 10
// 338.918 us; speedup vs baseline: 1.9814x; 1.9814x over previous
//
#include <hip/hip_runtime.h>
#include <hip/hip_bf16.h>

#define B_  4096
#define T_  255
#define V_  32000
#define E_  64
#define H_  64
#define D1_ 32

#define NCT           2000   // V/16 col-tiles
#define NCHUNK        10
#define CT_PER_CHUNK  200    // NCT / NCHUNK
#define CT_PER_WAVE   50     // CT_PER_CHUNK / 4 waves

typedef __attribute__((ext_vector_type(8))) short bf16x8;   // 8 bf16 = 4 VGPR
typedef __attribute__((ext_vector_type(4))) float f32x4;

__device__ __forceinline__ ushort f2bf(float f) {
    __hip_bfloat16 h = __float2bfloat16(f);   // RNE
    return *reinterpret_cast<ushort*>(&h);
}
__device__ __forceinline__ float fast_sigmoid(float x) {
    return __builtin_amdgcn_rcpf(1.f + __expf(-x));
}
// tanh with the 2x folded into prescaled weights (g gate scaled by 2.0):
// tanh_pre(y) = 1 - 2/(1+e^y) where y = 2x
__device__ __forceinline__ float fast_tanh_pre(float y) {
    return 1.f - 2.f * __builtin_amdgcn_rcpf(1.f + __expf(y));
}
__device__ __forceinline__ float fast_tanh(float x) {
    return 1.f - 2.f * __builtin_amdgcn_rcpf(1.f + __expf(2.f * x));
}

// Swizzled byte offset in a [16 rows][64 bf16] (128 B/row) h-tile.
__device__ __forceinline__ int hswz(int row, int colb) {
    return row * 128 + (colb ^ ((row & 7) << 4));
}

// ---------------------------------------------------------------------------
// Kernel 0 (merged): blocks [0,1000): emb fp32->bf16 ; [1000,1500): W2 repack.
// ---------------------------------------------------------------------------
__global__ __launch_bounds__(256)
void prep_kernel(const float* __restrict__ emb, ushort* __restrict__ emb_bf,
                 const float* __restrict__ W2,  ushort* __restrict__ w2p)
{
    if (blockIdx.x < 1000) {
        int i = blockIdx.x * 256 + threadIdx.x;      // over V*64/8 = 256000
        const float4 a = ((const float4*)emb)[i * 2];
        const float4 b = ((const float4*)emb)[i * 2 + 1];
        ushort t[8] = { f2bf(a.x), f2bf(a.y), f2bf(a.z), f2bf(a.w),
                        f2bf(b.x), f2bf(b.y), f2bf(b.z), f2bf(b.w) };
        *(ushort4*)(&emb_bf[i * 8])     = *(ushort4*)(&t[0]);
        *(ushort4*)(&emb_bf[i * 8 + 4]) = *(ushort4*)(&t[4]);
    } else {
        int t = (blockIdx.x - 1000) * 256 + threadIdx.x;   // over NCT*64
        if (t >= NCT * 64) return;
        int ct = t >> 6, l = t & 63;
        int kbase = (l >> 4) * 8, c = ct * 16 + (l & 15);
        ushort tmp[8];
        #pragma unroll
        for (int i = 0; i < 8; ++i)
            tmp[i] = f2bf(W2[(kbase + i) * V_ + c]);
        *(ushort4*)(&w2p[t * 8])     = *(ushort4*)(&tmp[0]);
        *(ushort4*)(&w2p[t * 8 + 4]) = *(ushort4*)(&tmp[4]);
    }
}

// ===========================================================================
// LSTM, bf16 MFMA, dual-slot x pipeline (R7 structure — measured 115 us),
// with head1 FUSED as an epilogue (waves 0-1: 2 MFMAs vs W1 + relu ->
// out32bf). g-gate weights prescaled by 2.0 (exact in bf16) so tanh(zg)
// needs no 2x multiply.
// ===========================================================================
__global__ __launch_bounds__(256)
void lstm_mfma_kernel(const int* __restrict__ idx,
                      const ushort* __restrict__ emb_bf,
                      const float* __restrict__ Wx,
                      const float* __restrict__ Wh,
                      const float* __restrict__ b,
                      const float* __restrict__ W1,
                      const float* __restrict__ b1,
                      ushort* __restrict__ out32bf)
{
    __shared__ __align__(16) char hbuf[2][2048];   // [buf][16 rows][64 bf16]
    __shared__ int idxs[16 * 257];                 // [row][t], stride 257

    const int tid  = threadIdx.x;
    const int lane = tid & 63;
    const int w    = tid >> 6;          // unit group
    const int r0   = blockIdx.x * 16;
    const int lrow = lane & 15;
    const int lhi  = lane >> 4;
    const int jcol = w * 16 + lrow;

    // persistent B fragments: 4 gates x 4 K-slices (s=0,1: Wx ; s=2,3: Wh)
    // gate 2 (cell input, tanh) prescaled by 2.0 — exact in bf16.
    bf16x8 bw[16];
    f32x4 bsp[4];                       // persistent bias splats (MFMA C-in)
    #pragma unroll
    for (int g = 0; g < 4; ++g) {
        const int col = g * 64 + jcol;
        const float sc = (g == 2) ? 2.f : 1.f;
        const float bv = b[col] * sc;
        bsp[g] = (f32x4){bv, bv, bv, bv};
        #pragma unroll
        for (int s = 0; s < 4; ++s) {
            bf16x8 f;
            #pragma unroll
            for (int i = 0; i < 8; ++i) {
                int k = s * 32 + lhi * 8 + i;
                float v = (k < 64) ? Wx[k * 256 + col] : Wh[(k - 64) * 256 + col];
                f[i] = (short)f2bf(v * sc);
            }
            bw[g * 4 + s] = f;
        }
    }

    // W1 B-frags for the fused head1 epilogue (waves 0,1 only)
    bf16x8 bw1[2];
    float b1v = 0.f;
    if (w < 2) {
        const int col = w * 16 + lrow;      // D1 column
        b1v = b1[col];
        #pragma unroll
        for (int s = 0; s < 2; ++s) {
            bf16x8 f;
            #pragma unroll
            for (int i = 0; i < 8; ++i)
                f[i] = (short)f2bf(W1[(s * 32 + lhi * 8 + i) * D1_ + col]);
            bw1[s] = f;
        }
    }

    {
        const int row = tid >> 4, tc = tid & 15;
        #pragma unroll
        for (int k = 0; k < 16; ++k) {
            int t = k * 16 + tc;
            if (t < T_) idxs[row * 257 + t] = idx[(r0 + row) * T_ + t];
        }
        ((float2*)hbuf[0])[tid] = make_float2(0.f, 0.f);
    }
    __syncthreads();

    // dual-slot x pipeline (no register rotation: true 2-step distance)
    bf16x8 xe0, xe1, xo0, xo1;
    {
        int iv = idxs[lrow * 257 + 0];
        xe0 = *(const bf16x8*)(emb_bf + iv * 64 + lhi * 8);
        xe1 = *(const bf16x8*)(emb_bf + iv * 64 + 32 + lhi * 8);
        iv = idxs[lrow * 257 + 1];
        xo0 = *(const bf16x8*)(emb_bf + iv * 64 + lhi * 8);
        xo1 = *(const bf16x8*)(emb_bf + iv * 64 + 32 + lhi * 8);
    }

    float cst[4]  = {0.f, 0.f, 0.f, 0.f};

    auto do_step = [&](int t, bf16x8& x0, bf16x8& x1) {
        const int p = t & 1;
        bf16x8 ah2 = *(const bf16x8*)(&hbuf[p][hswz(lrow, lhi * 16)]);
        bf16x8 ah3 = *(const bf16x8*)(&hbuf[p][hswz(lrow, 64 + lhi * 16)]);

        // z = bias + [x|h] @ W : 4 parallel gate chains, depth 4
        f32x4 z[4];
        #pragma unroll
        for (int g = 0; g < 4; ++g)
            z[g] = __builtin_amdgcn_mfma_f32_16x16x32_bf16(x0, bw[g * 4 + 0], bsp[g], 0, 0, 0);
        #pragma unroll
        for (int g = 0; g < 4; ++g)
            z[g] = __builtin_amdgcn_mfma_f32_16x16x32_bf16(x1, bw[g * 4 + 1], z[g], 0, 0, 0);
        #pragma unroll
        for (int g = 0; g < 4; ++g)
            z[g] = __builtin_amdgcn_mfma_f32_16x16x32_bf16(ah2, bw[g * 4 + 2], z[g], 0, 0, 0);
        #pragma unroll
        for (int g = 0; g < 4; ++g)
            z[g] = __builtin_amdgcn_mfma_f32_16x16x32_bf16(ah3, bw[g * 4 + 3], z[g], 0, 0, 0);

        // reload THIS slot for t+2 (in flight across 2 raw barriers)
        if (t + 2 < T_) {
            int iv = idxs[lrow * 257 + (t + 2)];
            x0 = *(const bf16x8*)(emb_bf + iv * 64 + lhi * 8);
            x1 = *(const bf16x8*)(emb_bf + iv * 64 + 32 + lhi * 8);
        }

        // activation (wave-local): lane owns unit jcol, batch rows lhi*4+r
        #pragma unroll
        for (int r = 0; r < 4; ++r) {
            float cn = fast_sigmoid(z[1][r]) * cst[r]
                     + fast_sigmoid(z[0][r]) * fast_tanh_pre(z[2][r]);
            cst[r] = cn;
            float hn = fast_sigmoid(z[3][r]) * fast_tanh(cn);
            const int row = lhi * 4 + r;
            *(ushort*)(&hbuf[p ^ 1][hswz(row, 2 * jcol)]) = f2bf(hn);
        }

        // LDS-only fence + raw barrier (global loads stay in flight)
        asm volatile("s_waitcnt lgkmcnt(0)\n\ts_barrier" ::: "memory");
    };

    for (int t = 0; t + 1 < T_; t += 2) {
        do_step(t,     xe0, xe1);
        do_step(t + 1, xo0, xo1);
    }
    do_step(T_ - 1, xe0, xe1);   // T_=255 odd: tail is an even-slot step

    // ---- fused head1: out32 = relu(h(T-1) @ W1 + b1), h from hbuf[1] ----
    if (w < 2) {
        bf16x8 e0 = *(const bf16x8*)(&hbuf[1][hswz(lrow, lhi * 16)]);
        bf16x8 e1 = *(const bf16x8*)(&hbuf[1][hswz(lrow, 64 + lhi * 16)]);
        f32x4 zz = (f32x4){b1v, b1v, b1v, b1v};
        zz = __builtin_amdgcn_mfma_f32_16x16x32_bf16(e0, bw1[0], zz, 0, 0, 0);
        zz = __builtin_amdgcn_mfma_f32_16x16x32_bf16(e1, bw1[1], zz, 0, 0, 0);
        #pragma unroll
        for (int r = 0; r < 4; ++r)
            out32bf[(r0 + lhi * 4 + r) * D1_ + w * 16 + lrow] =
                f2bf(fmaxf(zz[r], 0.f));
    }
}

// ---------------------------------------------------------------------------
// Kernel 3: logits = out32 @ W2 + b2, softmax over V, via MFMA.
// PASS 1: per-chunk row sums of exp; PASS 2: scaled write.
// ---------------------------------------------------------------------------
template <int PASS>
__global__ __launch_bounds__(256)
void head2_mfma_kernel(const ushort* __restrict__ out32bf,
                       const ushort* __restrict__ w2p,
                       const float* __restrict__ b2,
                       float* __restrict__ partial,   // [B][NCHUNK]
                       float* __restrict__ out)
{
    __shared__ float red[4][16];
    __shared__ float sinvs[16];

    const int tid  = threadIdx.x;
    const int lane = tid & 63;
    const int w    = tid >> 6;
    const int lrow = lane & 15;
    const int lhi  = lane >> 4;
    const int r0    = blockIdx.x * 16;
    const int chunk = blockIdx.y;

    if (PASS == 2) {
        if (tid < 16) {
            float s = 0.f;
            #pragma unroll
            for (int c = 0; c < NCHUNK; ++c) s += partial[(r0 + tid) * NCHUNK + c];
            sinvs[tid] = 1.f / s;
        }
        __syncthreads();
    }

    const bf16x8 A = *(const bf16x8*)(out32bf + (r0 + lrow) * D1_ + lhi * 8);

    float sacc[4] = {0.f, 0.f, 0.f, 0.f};
    float si[4];
    if (PASS == 2) {
        #pragma unroll
        for (int r = 0; r < 4; ++r) si[r] = sinvs[lhi * 4 + r];
    }

    const int ct0 = chunk * CT_PER_CHUNK + w * CT_PER_WAVE;
    for (int i = 0; i < CT_PER_WAVE; ++i) {
        const int ct = ct0 + i;
        const bf16x8 Bf = *(const bf16x8*)(w2p + ct * 512 + lane * 8);
        f32x4 z = __builtin_amdgcn_mfma_f32_16x16x32_bf16(A, Bf, (f32x4){0.f, 0.f, 0.f, 0.f}, 0, 0, 0);
        const float b2v = b2[ct * 16 + lrow];
        #pragma unroll
        for (int r = 0; r < 4; ++r) {
            float e = __expf(z[r] + b2v);
            if (PASS == 1) sacc[r] += e;
            else out[(size_t)(r0 + lhi * 4 + r) * V_ + ct * 16 + lrow] = e * si[r];
        }
    }

    if (PASS == 1) {
        #pragma unroll
        for (int r = 0; r < 4; ++r) {
            float v = sacc[r];
            #pragma unroll
            for (int off = 1; off < 16; off <<= 1) v += __shfl_xor(v, off, 16);
            if (lrow == 0) red[w][lhi * 4 + r] = v;
        }
        __syncthreads();
        if (tid < 16)
            partial[(r0 + tid) * NCHUNK + chunk] =
                red[0][tid] + red[1][tid] + red[2][tid] + red[3][tid];
    }
}

// ---------------------------------------------------------------------------
extern "C" void kernel_launch(void* const* d_in, const int* in_sizes, int n_in,
                              void* d_out, int out_size, void* d_ws, size_t ws_size,
                              hipStream_t stream)
{
    (void)in_sizes; (void)n_in; (void)out_size; (void)ws_size;

    const int*   idx = (const int*)  d_in[0];
    const float* emb = (const float*)d_in[1];
    const float* Wx  = (const float*)d_in[2];
    const float* Wh  = (const float*)d_in[3];
    const float* bl  = (const float*)d_in[4];
    const float* W1  = (const float*)d_in[5];
    const float* b1  = (const float*)d_in[6];
    const float* W2  = (const float*)d_in[7];
    const float* b2  = (const float*)d_in[8];
    float* out = (float*)d_out;

    float*  ws      = (float*)d_ws;
    ushort* out32bf = (ushort*)ws;                           // 131072 us = 65536 f
    ushort* w2p     = (ushort*)(ws + 65536);                 // 1024000 us = 512000 f
    float*  part    = ws + 65536 + 512000;                   // 40960 f32
    ushort* emb_bf  = (ushort*)(ws + 65536 + 512000 + 40960);  // 2048000 us

    prep_kernel<<<1500, 256, 0, stream>>>(emb, emb_bf, W2, w2p);
    lstm_mfma_kernel<<<256, 256, 0, stream>>>(idx, emb_bf, Wx, Wh, bl, W1, b1, out32bf);

    dim3 g3(B_ / 16, NCHUNK);
    head2_mfma_kernel<1><<<g3, 256, 0, stream>>>(out32bf, w2p, b2, part, out);
    head2_mfma_kernel<2><<<g3, 256, 0, stream>>>(out32bf, w2p, b2, part, out);
}